// Round 5
// baseline (175.360 us; speedup 1.0000x reference)
//
#include <hip/hip_runtime.h>

typedef __fp16   fp16x2  __attribute__((ext_vector_type(2)));
typedef _Float16 half4_t __attribute__((ext_vector_type(4)));
typedef unsigned uint2v  __attribute__((ext_vector_type(2)));
typedef float    f32x4   __attribute__((ext_vector_type(4)));

#define CH 4  // 64-sample chunks per wave

__device__ __forceinline__ unsigned pk(float a, float b) {
    fp16x2 h = __builtin_amdgcn_cvt_pkrtz(a, b);
    return __builtin_bit_cast(unsigned, h);
}
__device__ __forceinline__ half4_t mkfrag(unsigned lo, unsigned hi) {
    uint2v u; u[0] = lo; u[1] = hi;
    return __builtin_bit_cast(half4_t, u);
}
__device__ __forceinline__ float elu(float v) {
    return v > 0.f ? v : __expf(v) - 1.f;
}

// No LDS, no barriers. Each lane (g,m) builds its MFMA B-fragments directly:
// it loads the x-columns it needs for its k-slots and computes exactly the
// 4 cos + 4 sin values for freqs 4g..4g+3 of its samples. Feature slot
// layout (48): [x0..x8 | pad7 | cos0..15 | sin0..15]; A1 rows permuted to
// match, pad slots have A1 == 0 so garbage B values contribute nothing.
__global__ __launch_bounds__(128, 4) void pixenc_mfma3(
    const float* __restrict__ x,
    const float* __restrict__ Bl,
    const float* __restrict__ W1, const float* __restrict__ b1,
    const float* __restrict__ W2, const float* __restrict__ b2,
    const float* __restrict__ W3, const float* __restrict__ b3,
    const float* __restrict__ W4, const float* __restrict__ b4,
    const float* __restrict__ W5, const float* __restrict__ b5,
    float* __restrict__ out, int N)
{
    const int t    = threadIdx.x;
    const int lane = t & 63;
    const int w    = t >> 6;
    const int g    = lane >> 4;   // k-subgroup (freqs 4g..4g+3)
    const int m    = lane & 15;   // hidden idx (A) / sample col (B)

    // ---- per-lane weight fragments (A = W^T), biases as MFMA C-in ----
    half4_t A1[3], A2, A3, A4;
    #pragma unroll
    for (int c = 0; c < 3; ++c) {
        #pragma unroll
        for (int e = 0; e < 4; ++e) {
            const int slot = c * 16 + g * 4 + e;
            const int r = slot < 9 ? slot : slot - 7;   // W1 feature row
            const bool valid = (slot < 9) | (slot >= 16);
            A1[c][e] = valid ? (_Float16)W1[r * 16 + m] : (_Float16)0.f;
        }
    }
    #pragma unroll
    for (int e = 0; e < 4; ++e) {
        const int r = g * 4 + e;
        A2[e] = (_Float16)W2[r * 16 + m];
        A3[e] = (_Float16)W3[r * 16 + m];
        A4[e] = (_Float16)W4[r * 16 + m];
    }
    f32x4 c1, c2, c3, c4;
    float w5v[4];
    #pragma unroll
    for (int e = 0; e < 4; ++e) {
        const int r = g * 4 + e;
        c1[e] = b1[r]; c2[e] = b2[r]; c3[e] = b3[r]; c4[e] = b4[r];
        w5v[e] = W5[r];
    }
    const float b5v = b5[0];

    // Fourier weights for this lane's 4 freqs
    float blc[4], bls[4];
    #pragma unroll
    for (int e = 0; e < 4; ++e) {
        blc[e] = Bl[g * 4 + e];
        bls[e] = Bl[16 + g * 4 + e];
    }

    const int wavebase = blockIdx.x * (128 * CH) + w * (64 * CH);

    #pragma unroll
    for (int c = 0; c < CH; ++c) {
        const int sbase = wavebase + c * 64;

        // ---- issue all global loads for this chunk's 4 sub-batches ----
        float xc[4][4], x9[4], x10[4];
        #pragma unroll
        for (int s = 0; s < 4; ++s) {
            int j = sbase + s * 16 + m; if (j >= N) j = N - 1;
            const float* r = x + (size_t)j * 11;
            #pragma unroll
            for (int e = 0; e < 4; ++e) {
                const int col = g * 4 + e;
                xc[s][e] = r[col < 9 ? col : 0];   // pad slots: A1==0 kills it
            }
            x9[s] = r[9]; x10[s] = r[10];
        }

        // ---- per sub-batch: build B-frags in place, run the MLP chain ----
        #pragma unroll
        for (int s = 0; s < 4; ++s) {
            float cs[4], sn[4];
            #pragma unroll
            for (int e = 0; e < 4; ++e) {
                const float z = fmaf(x9[s], blc[e], x10[s] * bls[e]);
                const float zf = __builtin_amdgcn_fractf(z);
                cs[e] = __builtin_amdgcn_cosf(zf);
                sn[e] = __builtin_amdgcn_sinf(zf);
            }
            const half4_t f0 = mkfrag(pk(xc[s][0], xc[s][1]), pk(xc[s][2], xc[s][3]));
            const half4_t f1 = mkfrag(pk(cs[0], cs[1]), pk(cs[2], cs[3]));
            const half4_t f2 = mkfrag(pk(sn[0], sn[1]), pk(sn[2], sn[3]));

            f32x4 acc = c1;
            acc = __builtin_amdgcn_mfma_f32_16x16x16f16(A1[0], f0, acc, 0, 0, 0);
            acc = __builtin_amdgcn_mfma_f32_16x16x16f16(A1[1], f1, acc, 0, 0, 0);
            acc = __builtin_amdgcn_mfma_f32_16x16x16f16(A1[2], f2, acc, 0, 0, 0);

            half4_t h;
            #pragma unroll
            for (int e = 0; e < 4; ++e) h[e] = (_Float16)elu(acc[e]);
            acc = __builtin_amdgcn_mfma_f32_16x16x16f16(A2, h, c2, 0, 0, 0);
            #pragma unroll
            for (int e = 0; e < 4; ++e) h[e] = (_Float16)elu(acc[e]);
            acc = __builtin_amdgcn_mfma_f32_16x16x16f16(A3, h, c3, 0, 0, 0);
            #pragma unroll
            for (int e = 0; e < 4; ++e) h[e] = (_Float16)elu(acc[e]);
            acc = __builtin_amdgcn_mfma_f32_16x16x16f16(A4, h, c4, 0, 0, 0);

            float p = 0.f;
            #pragma unroll
            for (int e = 0; e < 4; ++e) p = fmaf(elu(acc[e]), w5v[e], p);
            p += __shfl_xor(p, 16, 64);
            p += __shfl_xor(p, 32, 64);

            const int o = sbase + s * 16 + m;
            if (g == 0 && o < N) out[o] = p + b5v;
        }
    }
}

extern "C" void kernel_launch(void* const* d_in, const int* in_sizes, int n_in,
                              void* d_out, int out_size, void* d_ws, size_t ws_size,
                              hipStream_t stream) {
    const float* x  = (const float*)d_in[0];
    const float* Bl = (const float*)d_in[1];
    const float* W1 = (const float*)d_in[2];
    const float* b1 = (const float*)d_in[3];
    const float* W2 = (const float*)d_in[4];
    const float* b2 = (const float*)d_in[5];
    const float* W3 = (const float*)d_in[6];
    const float* b3 = (const float*)d_in[7];
    const float* W4 = (const float*)d_in[8];
    const float* b4 = (const float*)d_in[9];
    const float* W5 = (const float*)d_in[10];
    const float* b5 = (const float*)d_in[11];
    float* out = (float*)d_out;

    const int N = out_size;
    const int blocks = (N + 128 * CH - 1) / (128 * CH);
    pixenc_mfma3<<<blocks, 128, 0, stream>>>(x, Bl, W1, b1, W2, b2, W3, b3,
                                             W4, b4, W5, b5, out, N);
}

// Round 6
// 146.604 us; speedup vs baseline: 1.1961x; 1.1961x over previous
//
#include <hip/hip_runtime.h>

typedef __fp16   cvt16x2 __attribute__((ext_vector_type(2)));
typedef _Float16 h2      __attribute__((ext_vector_type(2)));
typedef _Float16 half4_t __attribute__((ext_vector_type(4)));
typedef unsigned uint2v  __attribute__((ext_vector_type(2)));
typedef float    f32x4   __attribute__((ext_vector_type(4)));

#define CH 4  // 64-sample chunks per wave

#if !__has_builtin(__builtin_elementwise_exp2)
extern "C" __device__ _Float16 __ocml_exp2_f16(_Float16);
#endif

__device__ __forceinline__ unsigned pk(float a, float b) {
    cvt16x2 h = __builtin_amdgcn_cvt_pkrtz(a, b);
    return __builtin_bit_cast(unsigned, h);
}
__device__ __forceinline__ half4_t mkfrag(unsigned lo, unsigned hi) {
    uint2v u; u[0] = lo; u[1] = hi;
    return __builtin_bit_cast(half4_t, u);
}

// Packed fp16 ELU of an f32 pair -> packed fp16 pair, ready as MFMA operand.
// elu(v) = max(v,0) + (exp2(min(v,0)*log2e) - 1); (ev-1) is exact 0 for v>0.
__device__ __forceinline__ unsigned elu_pk(float a, float b) {
    h2 v = __builtin_bit_cast(h2, __builtin_amdgcn_cvt_pkrtz(a, b));
    const h2 z  = {(_Float16)0.f, (_Float16)0.f};
    const h2 lg = {(_Float16)1.44269504f, (_Float16)1.44269504f};
    const h2 m1 = {(_Float16)-1.f, (_Float16)-1.f};
    h2 mx = __builtin_elementwise_max(v, z);
    h2 mn = __builtin_elementwise_min(v, z);
    h2 tt = mn * lg;
#if __has_builtin(__builtin_elementwise_exp2)
    h2 ev = __builtin_elementwise_exp2(tt);
#else
    h2 ev; ev[0] = __ocml_exp2_f16(tt[0]); ev[1] = __ocml_exp2_f16(tt[1]);
#endif
    h2 r = mx + (ev + m1);
    return __builtin_bit_cast(unsigned, r);
}

// No LDS, no barriers. Lane (g,m) builds B-frags for its 4 samples directly.
// Layer-1 feature slot k = g*4+e holds, per c-chunk:
//   c=0: x[4e+g] (cols {g,4+g,8}; pads have A1==0)   c=1: cos[g*4+e]   c=2: sin[g*4+e]
// All 4 sub-batch MFMA chains run interleaved for ILP.
__global__ __launch_bounds__(128, 4) void pixenc_mfma4(
    const float* __restrict__ x,
    const float* __restrict__ Bl,
    const float* __restrict__ W1, const float* __restrict__ b1,
    const float* __restrict__ W2, const float* __restrict__ b2,
    const float* __restrict__ W3, const float* __restrict__ b3,
    const float* __restrict__ W4, const float* __restrict__ b4,
    const float* __restrict__ W5, const float* __restrict__ b5,
    float* __restrict__ out, int N)
{
    const int t    = threadIdx.x;
    const int lane = t & 63;
    const int w    = t >> 6;
    const int g    = lane >> 4;
    const int m    = lane & 15;

    // ---- per-lane weight fragments (A = W^T), biases as MFMA C-in ----
    half4_t A1[3], A2, A3, A4;
    #pragma unroll
    for (int e = 0; e < 4; ++e) {
        const int c0 = 4 * e + g;                     // load-friendly perm
        A1[0][e] = (c0 < 9) ? (_Float16)W1[c0 * 16 + m] : (_Float16)0.f;
        A1[1][e] = (_Float16)W1[(9  + g * 4 + e) * 16 + m];
        A1[2][e] = (_Float16)W1[(25 + g * 4 + e) * 16 + m];
        A2[e]    = (_Float16)W2[(g * 4 + e) * 16 + m];
        A3[e]    = (_Float16)W3[(g * 4 + e) * 16 + m];
        A4[e]    = (_Float16)W4[(g * 4 + e) * 16 + m];
    }
    f32x4 c1, c2, c3, c4;
    float w5v[4], blc[4], bls[4];
    #pragma unroll
    for (int e = 0; e < 4; ++e) {
        const int r = g * 4 + e;
        c1[e] = b1[r]; c2[e] = b2[r]; c3[e] = b3[r]; c4[e] = b4[r];
        w5v[e] = W5[r];
        blc[e] = Bl[r]; bls[e] = Bl[16 + r];
    }
    const float b5v = b5[0];

    const int wavebase = blockIdx.x * (128 * CH) + w * (64 * CH);

    for (int c = 0; c < CH; ++c) {
        const int sbase = wavebase + c * 64;

        // ---- phase A: load + build all 4 sub-batches' B-fragments ----
        float xg0[4], xg1[4], x8v[4], x9v[4], x10v[4];
        #pragma unroll
        for (int s = 0; s < 4; ++s) {
            int j = sbase + s * 16 + m; if (j >= N) j = N - 1;
            const float* rb = x + (size_t)j * 11;
            xg0[s] = rb[g];  xg1[s] = rb[4 + g];
            x8v[s] = rb[8];  x9v[s] = rb[9];  x10v[s] = rb[10];
        }

        half4_t F0[4], F1[4], F2[4];
        #pragma unroll
        for (int s = 0; s < 4; ++s) {
            float cs[4], sn[4];
            #pragma unroll
            for (int e = 0; e < 4; ++e) {
                float zz = fmaf(x9v[s], blc[e], x10v[s] * bls[e]);
                zz = __builtin_amdgcn_fractf(zz);   // revolutions -> [0,1)
                cs[e] = __builtin_amdgcn_cosf(zz);
                sn[e] = __builtin_amdgcn_sinf(zz);
            }
            F0[s] = mkfrag(pk(xg0[s], xg1[s]), pk(x8v[s], 0.f));
            F1[s] = mkfrag(pk(cs[0], cs[1]), pk(cs[2], cs[3]));
            F2[s] = mkfrag(pk(sn[0], sn[1]), pk(sn[2], sn[3]));
        }

        // ---- phase B: 4 independent MFMA chains, interleaved ----
        f32x4 acc[4];
        #pragma unroll
        for (int s = 0; s < 4; ++s) acc[s] = c1;
        #pragma unroll
        for (int s = 0; s < 4; ++s)
            acc[s] = __builtin_amdgcn_mfma_f32_16x16x16f16(A1[0], F0[s], acc[s], 0, 0, 0);
        #pragma unroll
        for (int s = 0; s < 4; ++s)
            acc[s] = __builtin_amdgcn_mfma_f32_16x16x16f16(A1[1], F1[s], acc[s], 0, 0, 0);
        #pragma unroll
        for (int s = 0; s < 4; ++s)
            acc[s] = __builtin_amdgcn_mfma_f32_16x16x16f16(A1[2], F2[s], acc[s], 0, 0, 0);

        half4_t H[4];
        #pragma unroll
        for (int s = 0; s < 4; ++s)
            H[s] = mkfrag(elu_pk(acc[s][0], acc[s][1]), elu_pk(acc[s][2], acc[s][3]));
        #pragma unroll
        for (int s = 0; s < 4; ++s)
            acc[s] = __builtin_amdgcn_mfma_f32_16x16x16f16(A2, H[s], c2, 0, 0, 0);

        #pragma unroll
        for (int s = 0; s < 4; ++s)
            H[s] = mkfrag(elu_pk(acc[s][0], acc[s][1]), elu_pk(acc[s][2], acc[s][3]));
        #pragma unroll
        for (int s = 0; s < 4; ++s)
            acc[s] = __builtin_amdgcn_mfma_f32_16x16x16f16(A3, H[s], c3, 0, 0, 0);

        #pragma unroll
        for (int s = 0; s < 4; ++s)
            H[s] = mkfrag(elu_pk(acc[s][0], acc[s][1]), elu_pk(acc[s][2], acc[s][3]));
        #pragma unroll
        for (int s = 0; s < 4; ++s)
            acc[s] = __builtin_amdgcn_mfma_f32_16x16x16f16(A4, H[s], c4, 0, 0, 0);

        // ---- head: 16 -> 1, fp32, reduce across the 4 g-groups ----
        #pragma unroll
        for (int s = 0; s < 4; ++s) {
            float p = 0.f;
            #pragma unroll
            for (int e = 0; e < 4; ++e) {
                const float v = acc[s][e];
                const float el = v > 0.f ? v : __expf(v) - 1.f;
                p = fmaf(el, w5v[e], p);
            }
            p += __shfl_xor(p, 16, 64);
            p += __shfl_xor(p, 32, 64);
            const int o = sbase + s * 16 + m;
            if (g == 0 && o < N) out[o] = p + b5v;
        }
    }
}

extern "C" void kernel_launch(void* const* d_in, const int* in_sizes, int n_in,
                              void* d_out, int out_size, void* d_ws, size_t ws_size,
                              hipStream_t stream) {
    const float* x  = (const float*)d_in[0];
    const float* Bl = (const float*)d_in[1];
    const float* W1 = (const float*)d_in[2];
    const float* b1 = (const float*)d_in[3];
    const float* W2 = (const float*)d_in[4];
    const float* b2 = (const float*)d_in[5];
    const float* W3 = (const float*)d_in[6];
    const float* b3 = (const float*)d_in[7];
    const float* W4 = (const float*)d_in[8];
    const float* b4 = (const float*)d_in[9];
    const float* W5 = (const float*)d_in[10];
    const float* b5 = (const float*)d_in[11];
    float* out = (float*)d_out;

    const int N = out_size;
    const int blocks = (N + 128 * CH - 1) / (128 * CH);
    pixenc_mfma4<<<blocks, 128, 0, stream>>>(x, Bl, W1, b1, W2, b2, W3, b3,
                                             W4, b4, W5, b5, out, N);
}

// Round 7
// 144.914 us; speedup vs baseline: 1.2101x; 1.0117x over previous
//
#include <hip/hip_runtime.h>

typedef __fp16   cvt16x2 __attribute__((ext_vector_type(2)));
typedef _Float16 h2      __attribute__((ext_vector_type(2)));
typedef _Float16 half4_t __attribute__((ext_vector_type(4)));
typedef unsigned uint2v  __attribute__((ext_vector_type(2)));
typedef float    f32x4   __attribute__((ext_vector_type(4)));

#define CH 4  // 64-sample chunks per wave

#if !__has_builtin(__builtin_elementwise_exp2)
extern "C" __device__ _Float16 __ocml_exp2_f16(_Float16);
#endif

__device__ __forceinline__ unsigned pk(float a, float b) {
    cvt16x2 h = __builtin_amdgcn_cvt_pkrtz(a, b);
    return __builtin_bit_cast(unsigned, h);
}
__device__ __forceinline__ half4_t mkfrag(unsigned lo, unsigned hi) {
    uint2v u; u[0] = lo; u[1] = hi;
    return __builtin_bit_cast(half4_t, u);
}

// Packed fp16 ELU of an f32 pair -> packed fp16 pair (MFMA-operand ready).
// elu(v) = max(v,0) + (exp2(min(v,0)*log2e) - 1); second term exact 0 for v>0.
__device__ __forceinline__ unsigned elu_pk(float a, float b) {
    h2 v = __builtin_bit_cast(h2, __builtin_amdgcn_cvt_pkrtz(a, b));
    const h2 z  = {(_Float16)0.f, (_Float16)0.f};
    const h2 lg = {(_Float16)1.44269504f, (_Float16)1.44269504f};
    const h2 m1 = {(_Float16)-1.f, (_Float16)-1.f};
    h2 mx = __builtin_elementwise_max(v, z);
    h2 mn = __builtin_elementwise_min(v, z);
    h2 tt = mn * lg;
#if __has_builtin(__builtin_elementwise_exp2)
    h2 ev = __builtin_elementwise_exp2(tt);
#else
    h2 ev; ev[0] = __ocml_exp2_f16(tt[0]); ev[1] = __ocml_exp2_f16(tt[1]);
#endif
    h2 r = mx + (ev + m1);
    return __builtin_bit_cast(unsigned, r);
}

__device__ __forceinline__ float hdot2(unsigned a, unsigned b, float c) {
#if __has_builtin(__builtin_amdgcn_fdot2)
    return __builtin_amdgcn_fdot2(__builtin_bit_cast(cvt16x2, a),
                                  __builtin_bit_cast(cvt16x2, b), c, false);
#else
    h2 av = __builtin_bit_cast(h2, a), bv = __builtin_bit_cast(h2, b);
    return fmaf((float)av[1], (float)bv[1], fmaf((float)av[0], (float)bv[0], c));
#endif
}

// No LDS, no barriers. Lane (g,m) builds B-frags for its 4 samples directly.
// Depth-1 register prefetch: chunk c+1's x-loads issue before chunk c's
// trans+MFMA work, giving ~1 chunk of compute to hide VMEM latency.
__global__ __launch_bounds__(128, 4) void pixenc_mfma5(
    const float* __restrict__ x,
    const float* __restrict__ Bl,
    const float* __restrict__ W1, const float* __restrict__ b1,
    const float* __restrict__ W2, const float* __restrict__ b2,
    const float* __restrict__ W3, const float* __restrict__ b3,
    const float* __restrict__ W4, const float* __restrict__ b4,
    const float* __restrict__ W5, const float* __restrict__ b5,
    float* __restrict__ out, int N)
{
    const int t    = threadIdx.x;
    const int lane = t & 63;
    const int w    = t >> 6;
    const int g    = lane >> 4;
    const int m    = lane & 15;

    // ---- per-lane weight fragments (A = W^T), biases as MFMA C-in ----
    half4_t A1[3], A2, A3, A4;
    #pragma unroll
    for (int e = 0; e < 4; ++e) {
        const int c0 = 4 * e + g;                     // load-friendly perm
        A1[0][e] = (c0 < 9) ? (_Float16)W1[c0 * 16 + m] : (_Float16)0.f;
        A1[1][e] = (_Float16)W1[(9  + g * 4 + e) * 16 + m];
        A1[2][e] = (_Float16)W1[(25 + g * 4 + e) * 16 + m];
        A2[e]    = (_Float16)W2[(g * 4 + e) * 16 + m];
        A3[e]    = (_Float16)W3[(g * 4 + e) * 16 + m];
        A4[e]    = (_Float16)W4[(g * 4 + e) * 16 + m];
    }
    f32x4 c1, c2, c3, c4;
    float blc[4], bls[4];
    #pragma unroll
    for (int e = 0; e < 4; ++e) {
        const int r = g * 4 + e;
        c1[e] = b1[r]; c2[e] = b2[r]; c3[e] = b3[r]; c4[e] = b4[r];
        blc[e] = Bl[r]; bls[e] = Bl[16 + r];
    }
    const unsigned w5p0 = pk(W5[g * 4 + 0], W5[g * 4 + 1]);
    const unsigned w5p1 = pk(W5[g * 4 + 2], W5[g * 4 + 3]);
    const float b5v = b5[0];

    const int wavebase = blockIdx.x * (128 * CH) + w * (64 * CH);

    // ---- prologue: load chunk 0 ----
    float xg0[4], xg1[4], x8v[4], x9v[4], x10v[4];
    #pragma unroll
    for (int s = 0; s < 4; ++s) {
        int j = wavebase + s * 16 + m; if (j >= N) j = N - 1;
        const float* rb = x + (size_t)j * 11;
        xg0[s] = rb[g];  xg1[s] = rb[4 + g];
        x8v[s] = rb[8];  x9v[s] = rb[9];  x10v[s] = rb[10];
    }

    #pragma unroll
    for (int c = 0; c < CH; ++c) {
        const int sbase = wavebase + c * 64;

        // ---- prefetch chunk c+1 (issued before any use of chunk c) ----
        float ng0[4], ng1[4], n8[4], n9[4], n10[4];
        if (c + 1 < CH) {
            #pragma unroll
            for (int s = 0; s < 4; ++s) {
                int j = sbase + 64 + s * 16 + m; if (j >= N) j = N - 1;
                const float* rb = x + (size_t)j * 11;
                ng0[s] = rb[g];  ng1[s] = rb[4 + g];
                n8[s]  = rb[8];  n9[s]  = rb[9];  n10[s] = rb[10];
            }
        }

        // ---- layer 1: per-s fragment build fused with its 3-MFMA chain ----
        f32x4 acc[4];
        #pragma unroll
        for (int s = 0; s < 4; ++s) {
            float cs[4], sn[4];
            #pragma unroll
            for (int e = 0; e < 4; ++e) {
                float zz = fmaf(x9v[s], blc[e], x10v[s] * bls[e]);
                zz = __builtin_amdgcn_fractf(zz);   // revolutions -> [0,1)
                cs[e] = __builtin_amdgcn_cosf(zz);
                sn[e] = __builtin_amdgcn_sinf(zz);
            }
            const half4_t F0 = mkfrag(pk(xg0[s], xg1[s]), pk(x8v[s], 0.f));
            const half4_t F1 = mkfrag(pk(cs[0], cs[1]), pk(cs[2], cs[3]));
            const half4_t F2 = mkfrag(pk(sn[0], sn[1]), pk(sn[2], sn[3]));
            f32x4 a = c1;
            a = __builtin_amdgcn_mfma_f32_16x16x16f16(A1[0], F0, a, 0, 0, 0);
            a = __builtin_amdgcn_mfma_f32_16x16x16f16(A1[1], F1, a, 0, 0, 0);
            a = __builtin_amdgcn_mfma_f32_16x16x16f16(A1[2], F2, a, 0, 0, 0);
            acc[s] = a;
        }

        // ---- layers 2-4: 4 independent chains, interleaved ----
        half4_t H[4];
        #pragma unroll
        for (int s = 0; s < 4; ++s)
            H[s] = mkfrag(elu_pk(acc[s][0], acc[s][1]), elu_pk(acc[s][2], acc[s][3]));
        #pragma unroll
        for (int s = 0; s < 4; ++s)
            acc[s] = __builtin_amdgcn_mfma_f32_16x16x16f16(A2, H[s], c2, 0, 0, 0);

        #pragma unroll
        for (int s = 0; s < 4; ++s)
            H[s] = mkfrag(elu_pk(acc[s][0], acc[s][1]), elu_pk(acc[s][2], acc[s][3]));
        #pragma unroll
        for (int s = 0; s < 4; ++s)
            acc[s] = __builtin_amdgcn_mfma_f32_16x16x16f16(A3, H[s], c3, 0, 0, 0);

        #pragma unroll
        for (int s = 0; s < 4; ++s)
            H[s] = mkfrag(elu_pk(acc[s][0], acc[s][1]), elu_pk(acc[s][2], acc[s][3]));
        #pragma unroll
        for (int s = 0; s < 4; ++s)
            acc[s] = __builtin_amdgcn_mfma_f32_16x16x16f16(A4, H[s], c4, 0, 0, 0);

        // ---- head: packed ELU + dot2, reduce across the 4 g-groups ----
        #pragma unroll
        for (int s = 0; s < 4; ++s) {
            const unsigned u0 = elu_pk(acc[s][0], acc[s][1]);
            const unsigned u1 = elu_pk(acc[s][2], acc[s][3]);
            float p = hdot2(u1, w5p1, hdot2(u0, w5p0, 0.f));
            p += __shfl_xor(p, 16, 64);
            p += __shfl_xor(p, 32, 64);
            const int o = sbase + s * 16 + m;
            if (g == 0 && o < N) out[o] = p + b5v;
        }

        // ---- rotate prefetch buffers ----
        if (c + 1 < CH) {
            #pragma unroll
            for (int s = 0; s < 4; ++s) {
                xg0[s] = ng0[s]; xg1[s] = ng1[s];
                x8v[s] = n8[s];  x9v[s] = n9[s];  x10v[s] = n10[s];
            }
        }
    }
}

extern "C" void kernel_launch(void* const* d_in, const int* in_sizes, int n_in,
                              void* d_out, int out_size, void* d_ws, size_t ws_size,
                              hipStream_t stream) {
    const float* x  = (const float*)d_in[0];
    const float* Bl = (const float*)d_in[1];
    const float* W1 = (const float*)d_in[2];
    const float* b1 = (const float*)d_in[3];
    const float* W2 = (const float*)d_in[4];
    const float* b2 = (const float*)d_in[5];
    const float* W3 = (const float*)d_in[6];
    const float* b3 = (const float*)d_in[7];
    const float* W4 = (const float*)d_in[8];
    const float* b4 = (const float*)d_in[9];
    const float* W5 = (const float*)d_in[10];
    const float* b5 = (const float*)d_in[11];
    float* out = (float*)d_out;

    const int N = out_size;
    const int blocks = (N + 128 * CH - 1) / (128 * CH);
    pixenc_mfma5<<<blocks, 128, 0, stream>>>(x, Bl, W1, b1, W2, b2, W3, b3,
                                             W4, b4, W5, b5, out, N);
}

// Round 8
// 137.744 us; speedup vs baseline: 1.2731x; 1.0521x over previous
//
#include <hip/hip_runtime.h>

typedef __fp16   cvt16x2 __attribute__((ext_vector_type(2)));
typedef _Float16 h2      __attribute__((ext_vector_type(2)));
typedef _Float16 half4_t __attribute__((ext_vector_type(4)));
typedef unsigned uint2v  __attribute__((ext_vector_type(2)));
typedef float    f32x4   __attribute__((ext_vector_type(4)));

#define CH 8   // 64-sample chunks per wave; 128-thread block => 1024 samples

#if !__has_builtin(__builtin_elementwise_exp2)
extern "C" __device__ _Float16 __ocml_exp2_f16(_Float16);
#endif

__device__ __forceinline__ unsigned pk(float a, float b) {
    cvt16x2 h = __builtin_amdgcn_cvt_pkrtz(a, b);
    return __builtin_bit_cast(unsigned, h);
}
__device__ __forceinline__ half4_t mkfrag(unsigned lo, unsigned hi) {
    uint2v u; u[0] = lo; u[1] = hi;
    return __builtin_bit_cast(half4_t, u);
}

// elu(v) = max(v, exp2(min(v,0)*log2e) - 1): packed fp16, 7 insts / 2 values.
// v>0: exp2(0)-1 = 0 -> max(v,0)=v.  v<=0: ev-1 >= v always -> ev-1.
__device__ __forceinline__ unsigned elu_pk(float a, float b) {
    h2 v = __builtin_bit_cast(h2, __builtin_amdgcn_cvt_pkrtz(a, b));
    const h2 z  = {(_Float16)0.f, (_Float16)0.f};
    const h2 lg = {(_Float16)1.44269504f, (_Float16)1.44269504f};
    const h2 m1 = {(_Float16)-1.f, (_Float16)-1.f};
    h2 t = __builtin_elementwise_min(v, z) * lg;
#if __has_builtin(__builtin_elementwise_exp2)
    h2 ev = __builtin_elementwise_exp2(t);
#else
    h2 ev; ev[0] = __ocml_exp2_f16(t[0]); ev[1] = __ocml_exp2_f16(t[1]);
#endif
    h2 r = __builtin_elementwise_max(v, ev + m1);
    return __builtin_bit_cast(unsigned, r);
}

__device__ __forceinline__ float hdot2(unsigned a, unsigned b, float c) {
#if __has_builtin(__builtin_amdgcn_fdot2)
    return __builtin_amdgcn_fdot2(__builtin_bit_cast(cvt16x2, a),
                                  __builtin_bit_cast(cvt16x2, b), c, false);
#else
    h2 av = __builtin_bit_cast(h2, a), bv = __builtin_bit_cast(h2, b);
    return fmaf((float)av[1], (float)bv[1], fmaf((float)av[0], (float)bv[0], c));
#endif
}

// Full-block kernel: NO bounds checks, incremental immediate-offset
// addressing, one coalesced 64-lane store per chunk. No LDS, no barriers.
__global__ __launch_bounds__(128, 4) void pixenc_mfma6(
    const float* __restrict__ x,
    const float* __restrict__ Bl,
    const float* __restrict__ W1, const float* __restrict__ b1,
    const float* __restrict__ W2, const float* __restrict__ b2,
    const float* __restrict__ W3, const float* __restrict__ b3,
    const float* __restrict__ W4, const float* __restrict__ b4,
    const float* __restrict__ W5, const float* __restrict__ b5,
    float* __restrict__ out)
{
    const int t    = threadIdx.x;
    const int lane = t & 63;
    const int w    = t >> 6;
    const int g    = lane >> 4;
    const int m    = lane & 15;

    // ---- per-lane weight fragments (A = W^T), biases as MFMA C-in ----
    half4_t A1[3], A2, A3, A4;
    #pragma unroll
    for (int e = 0; e < 4; ++e) {
        const int c0 = 4 * e + g;                 // layer-1 slot (g,e) -> x col
        A1[0][e] = (c0 < 9) ? (_Float16)W1[c0 * 16 + m] : (_Float16)0.f;
        A1[1][e] = (_Float16)W1[(9  + g * 4 + e) * 16 + m];
        A1[2][e] = (_Float16)W1[(25 + g * 4 + e) * 16 + m];
        A2[e]    = (_Float16)W2[(g * 4 + e) * 16 + m];
        A3[e]    = (_Float16)W3[(g * 4 + e) * 16 + m];
        A4[e]    = (_Float16)W4[(g * 4 + e) * 16 + m];
    }
    f32x4 c1, c2, c3, c4;
    float blc[4], bls[4];
    #pragma unroll
    for (int e = 0; e < 4; ++e) {
        const int r = g * 4 + e;
        c1[e] = b1[r]; c2[e] = b2[r]; c3[e] = b3[r]; c4[e] = b4[r];
        blc[e] = Bl[r]; bls[e] = Bl[16 + r];
    }
    const unsigned w5p0 = pk(W5[g * 4 + 0], W5[g * 4 + 1]);
    const unsigned w5p1 = pk(W5[g * 4 + 2], W5[g * 4 + 3]);
    const float b5v = b5[0];

    const int wavebase = blockIdx.x * (128 * CH) + w * (64 * CH);

    // per-lane base pointers; all loop loads use compile-time offsets
    const float* aA = x + (size_t)(wavebase + m) * 11 + g;   // cols g, 4+g(+16B)
    const float* aB = x + (size_t)(wavebase + m) * 11 + 8;   // cols 8,9,10
    float* outp = out + wavebase + lane;

    // ---- prologue: load+pack chunk 0 ----
    unsigned cp0[4], cp8[4];
    float cx9[4], cx10[4];
    #pragma unroll
    for (int s = 0; s < 4; ++s) {
        const float a0 = aA[s * 176], a1 = aA[s * 176 + 4];
        const float b8 = aB[s * 176], b9 = aB[s * 176 + 1], b10 = aB[s * 176 + 2];
        cp0[s] = pk(a0, a1); cp8[s] = pk(b8, 0.f);
        cx9[s] = b9; cx10[s] = b10;
    }

    #pragma unroll
    for (int c = 0; c < CH; ++c) {
        // ---- prefetch chunk c+1 (advance pointers, immediate offsets) ----
        unsigned np0[4], np8[4];
        float nx9[4], nx10[4];
        if (c + 1 < CH) {
            aA += 704; aB += 704;                 // 64 samples * 11 floats
            #pragma unroll
            for (int s = 0; s < 4; ++s) {
                const float a0 = aA[s * 176], a1 = aA[s * 176 + 4];
                const float b8 = aB[s * 176], b9 = aB[s * 176 + 1], b10 = aB[s * 176 + 2];
                np0[s] = pk(a0, a1); np8[s] = pk(b8, 0.f);
                nx9[s] = b9; nx10[s] = b10;
            }
        }

        // ---- layer 1: per-s fused fragment build + 3-MFMA chain ----
        f32x4 acc[4];
        #pragma unroll
        for (int s = 0; s < 4; ++s) {
            float cs[4], sn[4];
            #pragma unroll
            for (int e = 0; e < 4; ++e) {
                float zz = fmaf(cx9[s], blc[e], cx10[s] * bls[e]);
                zz = __builtin_amdgcn_fractf(zz);   // revolutions -> [0,1)
                cs[e] = __builtin_amdgcn_cosf(zz);
                sn[e] = __builtin_amdgcn_sinf(zz);
            }
            const half4_t F0 = mkfrag(cp0[s], cp8[s]);
            const half4_t F1 = mkfrag(pk(cs[0], cs[1]), pk(cs[2], cs[3]));
            const half4_t F2 = mkfrag(pk(sn[0], sn[1]), pk(sn[2], sn[3]));
            f32x4 a = c1;
            a = __builtin_amdgcn_mfma_f32_16x16x16f16(A1[0], F0, a, 0, 0, 0);
            a = __builtin_amdgcn_mfma_f32_16x16x16f16(A1[1], F1, a, 0, 0, 0);
            a = __builtin_amdgcn_mfma_f32_16x16x16f16(A1[2], F2, a, 0, 0, 0);
            acc[s] = a;
        }

        // ---- layers 2-4: 4 independent chains, interleaved ----
        half4_t H[4];
        #pragma unroll
        for (int s = 0; s < 4; ++s)
            H[s] = mkfrag(elu_pk(acc[s][0], acc[s][1]), elu_pk(acc[s][2], acc[s][3]));
        #pragma unroll
        for (int s = 0; s < 4; ++s)
            acc[s] = __builtin_amdgcn_mfma_f32_16x16x16f16(A2, H[s], c2, 0, 0, 0);

        #pragma unroll
        for (int s = 0; s < 4; ++s)
            H[s] = mkfrag(elu_pk(acc[s][0], acc[s][1]), elu_pk(acc[s][2], acc[s][3]));
        #pragma unroll
        for (int s = 0; s < 4; ++s)
            acc[s] = __builtin_amdgcn_mfma_f32_16x16x16f16(A3, H[s], c3, 0, 0, 0);

        #pragma unroll
        for (int s = 0; s < 4; ++s)
            H[s] = mkfrag(elu_pk(acc[s][0], acc[s][1]), elu_pk(acc[s][2], acc[s][3]));
        #pragma unroll
        for (int s = 0; s < 4; ++s)
            acc[s] = __builtin_amdgcn_mfma_f32_16x16x16f16(A4, H[s], c4, 0, 0, 0);

        // ---- head: packed ELU + dot2; reduce; one coalesced store ----
        float p[4];
        #pragma unroll
        for (int s = 0; s < 4; ++s) {
            const unsigned u0 = elu_pk(acc[s][0], acc[s][1]);
            const unsigned u1 = elu_pk(acc[s][2], acc[s][3]);
            p[s] = hdot2(u1, w5p1, hdot2(u0, w5p0, 0.f));
        }
        #pragma unroll
        for (int s = 0; s < 4; ++s) p[s] += __shfl_xor(p[s], 16, 64);
        #pragma unroll
        for (int s = 0; s < 4; ++s) p[s] += __shfl_xor(p[s], 32, 64);

        // lane (g,m) stores sub-batch s=g -> sample wavebase + c*64 + lane
        const float v01 = (g & 1) ? p[1] : p[0];
        const float v23 = (g & 1) ? p[3] : p[2];
        const float v   = (g & 2) ? v23 : v01;
        outp[c * 64] = v + b5v;

        // ---- rotate prefetch ----
        if (c + 1 < CH) {
            #pragma unroll
            for (int s = 0; s < 4; ++s) {
                cp0[s] = np0[s]; cp8[s] = np8[s];
                cx9[s] = nx9[s]; cx10[s] = nx10[s];
            }
        }
    }
}

// Guarded scalar tail (only launched when N % 1024 != 0; never for N=8388608).
__global__ void pixenc_tail(
    const float* __restrict__ x, const float* __restrict__ Bl,
    const float* __restrict__ W1, const float* __restrict__ b1,
    const float* __restrict__ W2, const float* __restrict__ b2,
    const float* __restrict__ W3, const float* __restrict__ b3,
    const float* __restrict__ W4, const float* __restrict__ b4,
    const float* __restrict__ W5, const float* __restrict__ b5,
    float* __restrict__ out, int N, int start)
{
    const int i = start + blockIdx.x * 256 + threadIdx.x;
    if (i >= N) return;
    const float* xr = x + (size_t)i * 11;
    float feats[41];
    for (int k = 0; k < 9; ++k) feats[k] = xr[k];
    for (int f = 0; f < 16; ++f) {
        const float ang = 6.283185f * (xr[9] * Bl[f] + xr[10] * Bl[16 + f]);
        float s, c; __sincosf(ang, &s, &c);
        feats[9 + f] = c; feats[25 + f] = s;
    }
    float h[16], gg[16];
    for (int j = 0; j < 16; ++j) h[j] = b1[j];
    for (int k = 0; k < 41; ++k)
        for (int j = 0; j < 16; ++j) h[j] = fmaf(feats[k], W1[k * 16 + j], h[j]);
    for (int j = 0; j < 16; ++j) h[j] = h[j] > 0.f ? h[j] : __expf(h[j]) - 1.f;
    for (int j = 0; j < 16; ++j) gg[j] = b2[j];
    for (int k = 0; k < 16; ++k)
        for (int j = 0; j < 16; ++j) gg[j] = fmaf(h[k], W2[k * 16 + j], gg[j]);
    for (int j = 0; j < 16; ++j) gg[j] = gg[j] > 0.f ? gg[j] : __expf(gg[j]) - 1.f;
    for (int j = 0; j < 16; ++j) h[j] = b3[j];
    for (int k = 0; k < 16; ++k)
        for (int j = 0; j < 16; ++j) h[j] = fmaf(gg[k], W3[k * 16 + j], h[j]);
    for (int j = 0; j < 16; ++j) h[j] = h[j] > 0.f ? h[j] : __expf(h[j]) - 1.f;
    for (int j = 0; j < 16; ++j) gg[j] = b4[j];
    for (int k = 0; k < 16; ++k)
        for (int j = 0; j < 16; ++j) gg[j] = fmaf(h[k], W4[k * 16 + j], gg[j]);
    for (int j = 0; j < 16; ++j) gg[j] = gg[j] > 0.f ? gg[j] : __expf(gg[j]) - 1.f;
    float o = b5[0];
    for (int j = 0; j < 16; ++j) o = fmaf(gg[j], W5[j], o);
    out[i] = o;
}

extern "C" void kernel_launch(void* const* d_in, const int* in_sizes, int n_in,
                              void* d_out, int out_size, void* d_ws, size_t ws_size,
                              hipStream_t stream) {
    const float* x  = (const float*)d_in[0];
    const float* Bl = (const float*)d_in[1];
    const float* W1 = (const float*)d_in[2];
    const float* b1 = (const float*)d_in[3];
    const float* W2 = (const float*)d_in[4];
    const float* b2 = (const float*)d_in[5];
    const float* W3 = (const float*)d_in[6];
    const float* b3 = (const float*)d_in[7];
    const float* W4 = (const float*)d_in[8];
    const float* b4 = (const float*)d_in[9];
    const float* W5 = (const float*)d_in[10];
    const float* b5 = (const float*)d_in[11];
    float* out = (float*)d_out;

    const int N = out_size;
    const int NB = N / (128 * CH);
    const int rem = N - NB * (128 * CH);
    if (NB > 0)
        pixenc_mfma6<<<NB, 128, 0, stream>>>(x, Bl, W1, b1, W2, b2, W3, b3,
                                             W4, b4, W5, b5, out);
    if (rem > 0)
        pixenc_tail<<<(rem + 255) / 256, 256, 0, stream>>>(
            x, Bl, W1, b1, W2, b2, W3, b3, W4, b4, W5, b5, out, N, NB * 128 * CH);
}

// Round 9
// 130.806 us; speedup vs baseline: 1.3406x; 1.0530x over previous
//
#include <hip/hip_runtime.h>

typedef __fp16   cvt16x2 __attribute__((ext_vector_type(2)));
typedef _Float16 h2      __attribute__((ext_vector_type(2)));
typedef _Float16 half4_t __attribute__((ext_vector_type(4)));
typedef unsigned uint2v  __attribute__((ext_vector_type(2)));
typedef float    f32x4   __attribute__((ext_vector_type(4)));

#define CH 8   // 64-sample chunks per wave; 128-thread block => 1024 samples

#if !__has_builtin(__builtin_elementwise_exp2)
extern "C" __device__ _Float16 __ocml_exp2_f16(_Float16);
#endif

__device__ __forceinline__ unsigned pk(float a, float b) {
    cvt16x2 h = __builtin_amdgcn_cvt_pkrtz(a, b);
    return __builtin_bit_cast(unsigned, h);
}
__device__ __forceinline__ half4_t mkfrag(unsigned lo, unsigned hi) {
    uint2v u; u[0] = lo; u[1] = hi;
    return __builtin_bit_cast(half4_t, u);
}

// elu(v) = max(v, exp2(min(v,0)*log2e) - 1): packed fp16, 7 insts / 2 values.
__device__ __forceinline__ unsigned elu_pk(float a, float b) {
    h2 v = __builtin_bit_cast(h2, __builtin_amdgcn_cvt_pkrtz(a, b));
    const h2 z  = {(_Float16)0.f, (_Float16)0.f};
    const h2 lg = {(_Float16)1.44269504f, (_Float16)1.44269504f};
    const h2 m1 = {(_Float16)-1.f, (_Float16)-1.f};
    h2 t = __builtin_elementwise_min(v, z) * lg;
#if __has_builtin(__builtin_elementwise_exp2)
    h2 ev = __builtin_elementwise_exp2(t);
#else
    h2 ev; ev[0] = __ocml_exp2_f16(t[0]); ev[1] = __ocml_exp2_f16(t[1]);
#endif
    h2 r = __builtin_elementwise_max(v, ev + m1);
    return __builtin_bit_cast(unsigned, r);
}

// No LDS, no barriers, no cross-lane shuffles. Per sub-batch of 16 samples:
//   z-MFMA   : z[f][samp] = x_light @ B_light  (D layout == what trans needs)
//   3 L1 MFMA + 3 mid MFMA (H^T chaining, D layout == next B layout)
//   head MFMA: W5 in A-row 0 -> D row 0 = outputs, direct coalesced store
__global__ __launch_bounds__(128, 4) void pixenc_mfma7(
    const float* __restrict__ x,
    const float* __restrict__ Bl,
    const float* __restrict__ W1, const float* __restrict__ b1,
    const float* __restrict__ W2, const float* __restrict__ b2,
    const float* __restrict__ W3, const float* __restrict__ b3,
    const float* __restrict__ W4, const float* __restrict__ b4,
    const float* __restrict__ W5, const float* __restrict__ b5,
    float* __restrict__ out)
{
    const int t    = threadIdx.x;
    const int lane = t & 63;
    const int w    = t >> 6;
    const int g    = lane >> 4;
    const int m    = lane & 15;

    // ---- per-lane weight fragments (A = W^T), biases as MFMA C-in ----
    half4_t A1[3], A2, A3, A4;
    #pragma unroll
    for (int e = 0; e < 4; ++e) {
        const int c0 = 4 * e + g;                 // layer-1 slot (g,e) -> x col
        A1[0][e] = (c0 < 9) ? (_Float16)W1[c0 * 16 + m] : (_Float16)0.f;
        A1[1][e] = (_Float16)W1[(9  + g * 4 + e) * 16 + m];
        A1[2][e] = (_Float16)W1[(25 + g * 4 + e) * 16 + m];
        A2[e]    = (_Float16)W2[(g * 4 + e) * 16 + m];
        A3[e]    = (_Float16)W3[(g * 4 + e) * 16 + m];
        A4[e]    = (_Float16)W4[(g * 4 + e) * 16 + m];
    }
    // z-MFMA A: A[row=f][k]: k=0 -> Bl_row0[f], k=1 -> Bl_row1[f]; rows=m.
    const half4_t Az = (g == 0) ? mkfrag(pk(Bl[m], Bl[16 + m]), 0u)
                                : mkfrag(0u, 0u);
    // head A: row 0 = W5
    const half4_t A5 = (m == 0)
        ? mkfrag(pk(W5[g * 4 + 0], W5[g * 4 + 1]), pk(W5[g * 4 + 2], W5[g * 4 + 3]))
        : mkfrag(0u, 0u);
    f32x4 c1, c2, c3, c4;
    #pragma unroll
    for (int e = 0; e < 4; ++e) {
        const int r = g * 4 + e;
        c1[e] = b1[r]; c2[e] = b2[r]; c3[e] = b3[r]; c4[e] = b4[r];
    }
    const float b5v = b5[0];
    const unsigned zmask = (g == 0) ? 0xFFFFFFFFu : 0u;   // B_z rows 0,1 only
    const f32x4 zero4 = {0.f, 0.f, 0.f, 0.f};

    const int wavebase = blockIdx.x * (128 * CH) + w * (64 * CH);

    // per-lane base pointers; all loop loads use compile-time offsets
    const float* aA = x + (size_t)(wavebase + m) * 11 + g;   // cols g, 4+g
    const float* aB = x + (size_t)(wavebase + m) * 11 + 8;   // cols 8,9,10
    float* outp = out + wavebase + m;

    // ---- prologue: load+pack chunk 0 ----
    unsigned cp0[4], cp8[4], cbz[4];
    #pragma unroll
    for (int s = 0; s < 4; ++s) {
        const float a0 = aA[s * 176], a1 = aA[s * 176 + 4];
        const float b8 = aB[s * 176], b9 = aB[s * 176 + 1], b10 = aB[s * 176 + 2];
        cp0[s] = pk(a0, a1); cp8[s] = pk(b8, 0.f);
        cbz[s] = pk(b9, b10) & zmask;
    }

    #pragma unroll
    for (int c = 0; c < CH; ++c) {
        // ---- prefetch chunk c+1 (advance pointers, immediate offsets) ----
        unsigned np0[4], np8[4], nbz[4];
        if (c + 1 < CH) {
            aA += 704; aB += 704;                 // 64 samples * 11 floats
            #pragma unroll
            for (int s = 0; s < 4; ++s) {
                const float a0 = aA[s * 176], a1 = aA[s * 176 + 4];
                const float b8 = aB[s * 176], b9 = aB[s * 176 + 1], b10 = aB[s * 176 + 2];
                np0[s] = pk(a0, a1); np8[s] = pk(b8, 0.f);
                nbz[s] = pk(b9, b10) & zmask;
            }
        }

        // ---- z-MFMAs for all 4 sub-batches (independent, pipelined) ----
        f32x4 az[4];
        #pragma unroll
        for (int s = 0; s < 4; ++s)
            az[s] = __builtin_amdgcn_mfma_f32_16x16x16f16(
                        Az, mkfrag(cbz[s], 0u), zero4, 0, 0, 0);

        // ---- layer 1: trans + fragment build + 3-MFMA chain per s ----
        f32x4 acc[4];
        #pragma unroll
        for (int s = 0; s < 4; ++s) {
            float cs[4], sn[4];
            #pragma unroll
            for (int e = 0; e < 4; ++e) {
                const float zf = __builtin_amdgcn_fractf(az[s][e]);
                cs[e] = __builtin_amdgcn_cosf(zf);
                sn[e] = __builtin_amdgcn_sinf(zf);
            }
            const half4_t F0 = mkfrag(cp0[s], cp8[s]);
            const half4_t F1 = mkfrag(pk(cs[0], cs[1]), pk(cs[2], cs[3]));
            const half4_t F2 = mkfrag(pk(sn[0], sn[1]), pk(sn[2], sn[3]));
            f32x4 a = c1;
            a = __builtin_amdgcn_mfma_f32_16x16x16f16(A1[0], F0, a, 0, 0, 0);
            a = __builtin_amdgcn_mfma_f32_16x16x16f16(A1[1], F1, a, 0, 0, 0);
            a = __builtin_amdgcn_mfma_f32_16x16x16f16(A1[2], F2, a, 0, 0, 0);
            acc[s] = a;
        }

        // ---- layers 2-4: 4 independent chains, interleaved ----
        half4_t H[4];
        #pragma unroll
        for (int s = 0; s < 4; ++s)
            H[s] = mkfrag(elu_pk(acc[s][0], acc[s][1]), elu_pk(acc[s][2], acc[s][3]));
        #pragma unroll
        for (int s = 0; s < 4; ++s)
            acc[s] = __builtin_amdgcn_mfma_f32_16x16x16f16(A2, H[s], c2, 0, 0, 0);

        #pragma unroll
        for (int s = 0; s < 4; ++s)
            H[s] = mkfrag(elu_pk(acc[s][0], acc[s][1]), elu_pk(acc[s][2], acc[s][3]));
        #pragma unroll
        for (int s = 0; s < 4; ++s)
            acc[s] = __builtin_amdgcn_mfma_f32_16x16x16f16(A3, H[s], c3, 0, 0, 0);

        #pragma unroll
        for (int s = 0; s < 4; ++s)
            H[s] = mkfrag(elu_pk(acc[s][0], acc[s][1]), elu_pk(acc[s][2], acc[s][3]));
        #pragma unroll
        for (int s = 0; s < 4; ++s)
            acc[s] = __builtin_amdgcn_mfma_f32_16x16x16f16(A4, H[s], c4, 0, 0, 0);

        // ---- head: ELU + head-MFMA; row 0 = outputs; coalesced 16-lane store
        #pragma unroll
        for (int s = 0; s < 4; ++s)
            H[s] = mkfrag(elu_pk(acc[s][0], acc[s][1]), elu_pk(acc[s][2], acc[s][3]));
        #pragma unroll
        for (int s = 0; s < 4; ++s) {
            const f32x4 oh = __builtin_amdgcn_mfma_f32_16x16x16f16(
                                 A5, H[s], zero4, 0, 0, 0);
            if (g == 0) outp[c * 64 + s * 16] = oh[0] + b5v;
        }

        // ---- rotate prefetch ----
        if (c + 1 < CH) {
            #pragma unroll
            for (int s = 0; s < 4; ++s) {
                cp0[s] = np0[s]; cp8[s] = np8[s]; cbz[s] = nbz[s];
            }
        }
    }
}

// Guarded scalar tail (only launched when N % 1024 != 0; never for N=8388608).
__global__ void pixenc_tail(
    const float* __restrict__ x, const float* __restrict__ Bl,
    const float* __restrict__ W1, const float* __restrict__ b1,
    const float* __restrict__ W2, const float* __restrict__ b2,
    const float* __restrict__ W3, const float* __restrict__ b3,
    const float* __restrict__ W4, const float* __restrict__ b4,
    const float* __restrict__ W5, const float* __restrict__ b5,
    float* __restrict__ out, int N, int start)
{
    const int i = start + blockIdx.x * 256 + threadIdx.x;
    if (i >= N) return;
    const float* xr = x + (size_t)i * 11;
    float feats[41];
    for (int k = 0; k < 9; ++k) feats[k] = xr[k];
    for (int f = 0; f < 16; ++f) {
        const float ang = 6.283185f * (xr[9] * Bl[f] + xr[10] * Bl[16 + f]);
        float s, c; __sincosf(ang, &s, &c);
        feats[9 + f] = c; feats[25 + f] = s;
    }
    float h[16], gg[16];
    for (int j = 0; j < 16; ++j) h[j] = b1[j];
    for (int k = 0; k < 41; ++k)
        for (int j = 0; j < 16; ++j) h[j] = fmaf(feats[k], W1[k * 16 + j], h[j]);
    for (int j = 0; j < 16; ++j) h[j] = h[j] > 0.f ? h[j] : __expf(h[j]) - 1.f;
    for (int j = 0; j < 16; ++j) gg[j] = b2[j];
    for (int k = 0; k < 16; ++k)
        for (int j = 0; j < 16; ++j) gg[j] = fmaf(h[k], W2[k * 16 + j], gg[j]);
    for (int j = 0; j < 16; ++j) gg[j] = gg[j] > 0.f ? gg[j] : __expf(gg[j]) - 1.f;
    for (int j = 0; j < 16; ++j) h[j] = b3[j];
    for (int k = 0; k < 16; ++k)
        for (int j = 0; j < 16; ++j) h[j] = fmaf(gg[k], W3[k * 16 + j], h[j]);
    for (int j = 0; j < 16; ++j) h[j] = h[j] > 0.f ? h[j] : __expf(h[j]) - 1.f;
    for (int j = 0; j < 16; ++j) gg[j] = b4[j];
    for (int k = 0; k < 16; ++k)
        for (int j = 0; j < 16; ++j) gg[j] = fmaf(h[k], W4[k * 16 + j], gg[j]);
    for (int j = 0; j < 16; ++j) gg[j] = gg[j] > 0.f ? gg[j] : __expf(gg[j]) - 1.f;
    float o = b5[0];
    for (int j = 0; j < 16; ++j) o = fmaf(gg[j], W5[j], o);
    out[i] = o;
}

extern "C" void kernel_launch(void* const* d_in, const int* in_sizes, int n_in,
                              void* d_out, int out_size, void* d_ws, size_t ws_size,
                              hipStream_t stream) {
    const float* x  = (const float*)d_in[0];
    const float* Bl = (const float*)d_in[1];
    const float* W1 = (const float*)d_in[2];
    const float* b1 = (const float*)d_in[3];
    const float* W2 = (const float*)d_in[4];
    const float* b2 = (const float*)d_in[5];
    const float* W3 = (const float*)d_in[6];
    const float* b3 = (const float*)d_in[7];
    const float* W4 = (const float*)d_in[8];
    const float* b4 = (const float*)d_in[9];
    const float* W5 = (const float*)d_in[10];
    const float* b5 = (const float*)d_in[11];
    float* out = (float*)d_out;

    const int N = out_size;
    const int NB = N / (128 * CH);
    const int rem = N - NB * (128 * CH);
    if (NB > 0)
        pixenc_mfma7<<<NB, 128, 0, stream>>>(x, Bl, W1, b1, W2, b2, W3, b3,
                                             W4, b4, W5, b5, out);
    if (rem > 0)
        pixenc_tail<<<(rem + 255) / 256, 256, 0, stream>>>(
            x, Bl, W1, b1, W2, b2, W3, b3, W4, b4, W5, b5, out, N, NB * 128 * CH);
}

// Round 10
// 127.119 us; speedup vs baseline: 1.3795x; 1.0290x over previous
//
#include <hip/hip_runtime.h>

typedef __fp16   cvt16x2 __attribute__((ext_vector_type(2)));
typedef _Float16 h2      __attribute__((ext_vector_type(2)));
typedef _Float16 half4_t __attribute__((ext_vector_type(4)));
typedef unsigned uint2v  __attribute__((ext_vector_type(2)));
typedef float    f32x4   __attribute__((ext_vector_type(4)));

#define CH 8   // 64-sample chunks per wave; 128-thread block => 1024 samples
#define LOG2E 1.44269504f
#define LN2   0.69314718f

#if !__has_builtin(__builtin_elementwise_exp2)
extern "C" __device__ _Float16 __ocml_exp2_f16(_Float16);
#endif

__device__ __forceinline__ unsigned pk(float a, float b) {
    cvt16x2 h = __builtin_amdgcn_cvt_pkrtz(a, b);
    return __builtin_bit_cast(unsigned, h);
}
__device__ __forceinline__ half4_t mkfrag(unsigned lo, unsigned hi) {
    uint2v u; u[0] = lo; u[1] = hi;
    return __builtin_bit_cast(half4_t, u);
}

// Scaled-domain ELU. Input v' = v*log2e (weights pre-scaled); output
// H' = elu(v)*log2e = max(v', exp2(min(v',0))*lg - lg). 4 pk-ops + 2 trans.
__device__ __forceinline__ unsigned elu_pk(float a, float b) {
    h2 v = __builtin_bit_cast(h2, __builtin_amdgcn_cvt_pkrtz(a, b));
    const h2 z   = {(_Float16)0.f, (_Float16)0.f};
    const h2 lg  = {(_Float16)LOG2E, (_Float16)LOG2E};
    const h2 mlg = {(_Float16)(-LOG2E), (_Float16)(-LOG2E)};
    h2 t = __builtin_elementwise_min(v, z);
#if __has_builtin(__builtin_elementwise_exp2)
    h2 ev = __builtin_elementwise_exp2(t);
#else
    h2 ev; ev[0] = __ocml_exp2_f16(t[0]); ev[1] = __ocml_exp2_f16(t[1]);
#endif
    h2 r = __builtin_elementwise_max(v, ev * lg + mlg);   // v_pk_fma_f16
    return __builtin_bit_cast(unsigned, r);
}

// No LDS, no barriers, no shuffles, no masks. Per sub-batch of 16 samples:
// z-MFMA -> sincos -> 3 L1 MFMAs -> 3x(ELU+MFMA) -> ELU+head MFMA -> store.
// All accumulators live in the *log2e-scaled domain*; A2..A4 are unchanged
// (log2e*ln2 == 1), A5 carries the ln2 un-scaling, b5 rides in head C-in.
__global__ __launch_bounds__(128, 4) void pixenc_mfma8(
    const float* __restrict__ x,
    const float* __restrict__ Bl,
    const float* __restrict__ W1, const float* __restrict__ b1,
    const float* __restrict__ W2, const float* __restrict__ b2,
    const float* __restrict__ W3, const float* __restrict__ b3,
    const float* __restrict__ W4, const float* __restrict__ b4,
    const float* __restrict__ W5, const float* __restrict__ b5,
    float* __restrict__ out)
{
    const int t    = threadIdx.x;
    const int lane = t & 63;
    const int w    = t >> 6;
    const int g    = lane >> 4;
    const int m    = lane & 15;

    // ---- per-lane weight fragments; A1/c1..c4 pre-scaled by log2e ----
    half4_t A1[3], A2, A3, A4;
    #pragma unroll
    for (int e = 0; e < 4; ++e) {
        const int c0 = 4 * e + g;                 // layer-1 slot (g,e) -> x col
        A1[0][e] = (c0 < 9) ? (_Float16)(W1[c0 * 16 + m] * LOG2E) : (_Float16)0.f;
        A1[1][e] = (_Float16)(W1[(9  + g * 4 + e) * 16 + m] * LOG2E);
        A1[2][e] = (_Float16)(W1[(25 + g * 4 + e) * 16 + m] * LOG2E);
        A2[e]    = (_Float16)W2[(g * 4 + e) * 16 + m];
        A3[e]    = (_Float16)W3[(g * 4 + e) * 16 + m];
        A4[e]    = (_Float16)W4[(g * 4 + e) * 16 + m];
    }
    // z-MFMA A: row f: k0 -> Bl_row0[f], k1 -> Bl_row1[f]; zero cols k>=2.
    const half4_t Az = (g == 0) ? mkfrag(pk(Bl[m], Bl[16 + m]), 0u)
                                : mkfrag(0u, 0u);
    // head A: row 0 = W5 * ln2 (un-scales H4' = log2e*H4)
    const half4_t A5 = (m == 0)
        ? mkfrag(pk(W5[g * 4 + 0] * LN2, W5[g * 4 + 1] * LN2),
                 pk(W5[g * 4 + 2] * LN2, W5[g * 4 + 3] * LN2))
        : mkfrag(0u, 0u);
    f32x4 c1, c2, c3, c4;
    #pragma unroll
    for (int e = 0; e < 4; ++e) {
        const int r = g * 4 + e;
        c1[e] = b1[r] * LOG2E; c2[e] = b2[r] * LOG2E;
        c3[e] = b3[r] * LOG2E; c4[e] = b4[r] * LOG2E;
    }
    const f32x4 zero4 = {0.f, 0.f, 0.f, 0.f};
    f32x4 c5 = zero4;
    if (g == 0) c5[0] = b5[0];                    // b5 via head C-in row 0

    const int wavebase = blockIdx.x * (128 * CH) + w * (64 * CH);

    // per-lane base pointers; all loop loads use compile-time offsets
    const float* aA = x + (size_t)(wavebase + m) * 11 + g;   // cols g, 4+g
    const float* aB = x + (size_t)(wavebase + m) * 11 + 8;   // cols 8,9,10
    float* outp = out + wavebase + m;

    // ---- prologue: load+pack chunk 0 ----
    unsigned cp0[4], cp8[4], cbz[4];
    #pragma unroll
    for (int s = 0; s < 4; ++s) {
        const float a0 = aA[s * 176], a1 = aA[s * 176 + 4];
        const float b8 = aB[s * 176], b9 = aB[s * 176 + 1], b10 = aB[s * 176 + 2];
        cp0[s] = pk(a0, a1); cp8[s] = pk(b8, 0.f);
        cbz[s] = pk(b9, b10);          // garbage B-rows k>=4 hit zero A cols
    }

    #pragma unroll
    for (int c = 0; c < CH; ++c) {
        // ---- prefetch chunk c+1 (advance pointers, immediate offsets) ----
        unsigned np0[4], np8[4], nbz[4];
        if (c + 1 < CH) {
            aA += 704; aB += 704;                 // 64 samples * 11 floats
            #pragma unroll
            for (int s = 0; s < 4; ++s) {
                const float a0 = aA[s * 176], a1 = aA[s * 176 + 4];
                const float b8 = aB[s * 176], b9 = aB[s * 176 + 1], b10 = aB[s * 176 + 2];
                np0[s] = pk(a0, a1); np8[s] = pk(b8, 0.f);
                nbz[s] = pk(b9, b10);
            }
        }

        // ---- z-MFMAs for all 4 sub-batches (independent, pipelined) ----
        f32x4 az[4];
        #pragma unroll
        for (int s = 0; s < 4; ++s)
            az[s] = __builtin_amdgcn_mfma_f32_16x16x16f16(
                        Az, mkfrag(cbz[s], 0u), zero4, 0, 0, 0);

        // ---- layer 1: trans + fragment build + 3-MFMA chain per s ----
        f32x4 acc[4];
        #pragma unroll
        for (int s = 0; s < 4; ++s) {
            float cs[4], sn[4];
            #pragma unroll
            for (int e = 0; e < 4; ++e) {
                const float zf = __builtin_amdgcn_fractf(az[s][e]);
                cs[e] = __builtin_amdgcn_cosf(zf);
                sn[e] = __builtin_amdgcn_sinf(zf);
            }
            const half4_t F0 = mkfrag(cp0[s], cp8[s]);
            const half4_t F1 = mkfrag(pk(cs[0], cs[1]), pk(cs[2], cs[3]));
            const half4_t F2 = mkfrag(pk(sn[0], sn[1]), pk(sn[2], sn[3]));
            f32x4 a = c1;
            a = __builtin_amdgcn_mfma_f32_16x16x16f16(A1[0], F0, a, 0, 0, 0);
            a = __builtin_amdgcn_mfma_f32_16x16x16f16(A1[1], F1, a, 0, 0, 0);
            a = __builtin_amdgcn_mfma_f32_16x16x16f16(A1[2], F2, a, 0, 0, 0);
            acc[s] = a;
        }

        // ---- layers 2-4: 4 independent chains, interleaved ----
        half4_t H[4];
        #pragma unroll
        for (int s = 0; s < 4; ++s)
            H[s] = mkfrag(elu_pk(acc[s][0], acc[s][1]), elu_pk(acc[s][2], acc[s][3]));
        #pragma unroll
        for (int s = 0; s < 4; ++s)
            acc[s] = __builtin_amdgcn_mfma_f32_16x16x16f16(A2, H[s], c2, 0, 0, 0);

        #pragma unroll
        for (int s = 0; s < 4; ++s)
            H[s] = mkfrag(elu_pk(acc[s][0], acc[s][1]), elu_pk(acc[s][2], acc[s][3]));
        #pragma unroll
        for (int s = 0; s < 4; ++s)
            acc[s] = __builtin_amdgcn_mfma_f32_16x16x16f16(A3, H[s], c3, 0, 0, 0);

        #pragma unroll
        for (int s = 0; s < 4; ++s)
            H[s] = mkfrag(elu_pk(acc[s][0], acc[s][1]), elu_pk(acc[s][2], acc[s][3]));
        #pragma unroll
        for (int s = 0; s < 4; ++s)
            acc[s] = __builtin_amdgcn_mfma_f32_16x16x16f16(A4, H[s], c4, 0, 0, 0);

        // ---- head: ELU + head-MFMA (b5 in C); row 0 = outputs; store ----
        #pragma unroll
        for (int s = 0; s < 4; ++s)
            H[s] = mkfrag(elu_pk(acc[s][0], acc[s][1]), elu_pk(acc[s][2], acc[s][3]));
        #pragma unroll
        for (int s = 0; s < 4; ++s) {
            const f32x4 oh = __builtin_amdgcn_mfma_f32_16x16x16f16(
                                 A5, H[s], c5, 0, 0, 0);
            if (g == 0) outp[c * 64 + s * 16] = oh[0];
        }

        // ---- rotate prefetch ----
        if (c + 1 < CH) {
            #pragma unroll
            for (int s = 0; s < 4; ++s) {
                cp0[s] = np0[s]; cp8[s] = np8[s]; cbz[s] = nbz[s];
            }
        }
    }
}

// Guarded scalar tail (only launched when N % 1024 != 0; never for N=8388608).
__global__ void pixenc_tail(
    const float* __restrict__ x, const float* __restrict__ Bl,
    const float* __restrict__ W1, const float* __restrict__ b1,
    const float* __restrict__ W2, const float* __restrict__ b2,
    const float* __restrict__ W3, const float* __restrict__ b3,
    const float* __restrict__ W4, const float* __restrict__ b4,
    const float* __restrict__ W5, const float* __restrict__ b5,
    float* __restrict__ out, int N, int start)
{
    const int i = start + blockIdx.x * 256 + threadIdx.x;
    if (i >= N) return;
    const float* xr = x + (size_t)i * 11;
    float feats[41];
    for (int k = 0; k < 9; ++k) feats[k] = xr[k];
    for (int f = 0; f < 16; ++f) {
        const float ang = 6.283185f * (xr[9] * Bl[f] + xr[10] * Bl[16 + f]);
        float s, c; __sincosf(ang, &s, &c);
        feats[9 + f] = c; feats[25 + f] = s;
    }
    float h[16], gg[16];
    for (int j = 0; j < 16; ++j) h[j] = b1[j];
    for (int k = 0; k < 41; ++k)
        for (int j = 0; j < 16; ++j) h[j] = fmaf(feats[k], W1[k * 16 + j], h[j]);
    for (int j = 0; j < 16; ++j) h[j] = h[j] > 0.f ? h[j] : __expf(h[j]) - 1.f;
    for (int j = 0; j < 16; ++j) gg[j] = b2[j];
    for (int k = 0; k < 16; ++k)
        for (int j = 0; j < 16; ++j) gg[j] = fmaf(h[k], W2[k * 16 + j], gg[j]);
    for (int j = 0; j < 16; ++j) gg[j] = gg[j] > 0.f ? gg[j] : __expf(gg[j]) - 1.f;
    for (int j = 0; j < 16; ++j) h[j] = b3[j];
    for (int k = 0; k < 16; ++k)
        for (int j = 0; j < 16; ++j) h[j] = fmaf(gg[k], W3[k * 16 + j], h[j]);
    for (int j = 0; j < 16; ++j) h[j] = h[j] > 0.f ? h[j] : __expf(h[j]) - 1.f;
    for (int j = 0; j < 16; ++j) gg[j] = b4[j];
    for (int k = 0; k < 16; ++k)
        for (int j = 0; j < 16; ++j) gg[j] = fmaf(h[k], W4[k * 16 + j], gg[j]);
    for (int j = 0; j < 16; ++j) gg[j] = gg[j] > 0.f ? gg[j] : __expf(gg[j]) - 1.f;
    float o = b5[0];
    for (int j = 0; j < 16; ++j) o = fmaf(gg[j], W5[j], o);
    out[i] = o;
}

extern "C" void kernel_launch(void* const* d_in, const int* in_sizes, int n_in,
                              void* d_out, int out_size, void* d_ws, size_t ws_size,
                              hipStream_t stream) {
    const float* x  = (const float*)d_in[0];
    const float* Bl = (const float*)d_in[1];
    const float* W1 = (const float*)d_in[2];
    const float* b1 = (const float*)d_in[3];
    const float* W2 = (const float*)d_in[4];
    const float* b2 = (const float*)d_in[5];
    const float* W3 = (const float*)d_in[6];
    const float* b3 = (const float*)d_in[7];
    const float* W4 = (const float*)d_in[8];
    const float* b4 = (const float*)d_in[9];
    const float* W5 = (const float*)d_in[10];
    const float* b5 = (const float*)d_in[11];
    float* out = (float*)d_out;

    const int N = out_size;
    const int NB = N / (128 * CH);
    const int rem = N - NB * (128 * CH);
    if (NB > 0)
        pixenc_mfma8<<<NB, 128, 0, stream>>>(x, Bl, W1, b1, W2, b2, W3, b3,
                                             W4, b4, W5, b5, out);
    if (rem > 0)
        pixenc_tail<<<(rem + 255) / 256, 256, 0, stream>>>(
            x, Bl, W1, b1, W2, b2, W3, b3, W4, b4, W5, b5, out, N, NB * 128 * CH);
}